// Round 4
// baseline (7730.027 us; speedup 1.0000x reference)
//
#include <hip/hip_runtime.h>
#include <hip/hip_bf16.h>
#include <math.h>

// Problem constants
#define B_    8
#define N1_   4096
#define N2_   4096
#define C_    512
#define P_    256
#define H_    8
#define MLP_  2048
#define HD_   64

typedef __hip_bfloat16 bf16;

__device__ __forceinline__ float bf2f(bf16 v) { return __bfloat162float(v); }
__device__ __forceinline__ bf16  f2bf(float v) { return __float2bfloat16(v); }
__device__ __forceinline__ float ubf2f(unsigned short u) {
  union { float f; unsigned int i; } cv; cv.i = ((unsigned int)u) << 16; return cv.f;
}
__device__ __forceinline__ float gelu_exact(float x) {
  return 0.5f * x * (1.0f + erff(x * 0.70710678118654752f));
}

// Generic tiled GEMM: C = op(A) @ B (+bias +pos) with optional gelu.
// Inputs (x1/x2/weights/bias/pos) are FLOAT32; internal activations are bf16.
// AF32=1: A is f32. AF32=0: A is bf16 (internal buffers).
// TRANSA=0: A is (M,K) row-major. TRANSA=1: A is (K,M) row-major (kp/vp einsum,
//           bf16 only). B is always f32, (K,N) row-major.
// Batched over blockIdx.z: A offset = (z/aInnerCnt)*aOuter + (z%aInnerCnt)*aInner
// elements, C offset = z*cBatch. Tile 64x64, BK=16, 256 thr, 4x4/thr, tx+16j swizzle.
template<int TRANSA, int AF32, int OUTF32, int ACT>
__global__ __launch_bounds__(256) void gemm_kernel(
    const void* __restrict__ A, const float* __restrict__ Bm,
    const float* __restrict__ bias, const float* __restrict__ pos, int posmask,
    void* __restrict__ Cv, int M, int N, int K, int lda, int ldb,
    long aOuter, int aInnerCnt, int aInner, long cBatch)
{
  __shared__ float As[16][65];
  __shared__ float Bs[16][65];
  const int z = blockIdx.z;
  const long aoff = (long)(z / aInnerCnt) * aOuter + (long)(z % aInnerCnt) * aInner;
  const int n0 = blockIdx.x * 64;
  const int m0 = blockIdx.y * 64;
  const int t  = threadIdx.x;
  const int tx = t & 15, ty = t >> 4;
  float acc[4][4] = {};
  for (int k0 = 0; k0 < K; k0 += 16) {
    if (TRANSA) {   // bf16 A, (K,M) layout
      const bf16* Ab = (const bf16*)A + aoff;
      const int mm = t & 63, kk = t >> 6;
      #pragma unroll
      for (int i = 0; i < 4; ++i)
        As[kk + 4*i][mm] = bf2f(Ab[(size_t)(k0 + kk + 4*i) * lda + m0 + mm]);
    } else if (AF32) {   // f32 A, (M,K): 4 consecutive k per thread, 16B load
      const float* Ab = (const float*)A + aoff;
      const int mm = t >> 2, kk4 = (t & 3) * 4;
      const float4 av = *(const float4*)(Ab + (size_t)(m0 + mm) * lda + k0 + kk4);
      As[kk4+0][mm] = av.x;
      As[kk4+1][mm] = av.y;
      As[kk4+2][mm] = av.z;
      As[kk4+3][mm] = av.w;
    } else {             // bf16 A, (M,K): 8B vec load
      const bf16* Ab = (const bf16*)A + aoff;
      const int mm = t >> 2, kk4 = (t & 3) * 4;
      const ushort4 av = *(const ushort4*)(Ab + (size_t)(m0 + mm) * lda + k0 + kk4);
      As[kk4+0][mm] = ubf2f(av.x);
      As[kk4+1][mm] = ubf2f(av.y);
      As[kk4+2][mm] = ubf2f(av.z);
      As[kk4+3][mm] = ubf2f(av.w);
    }
    {
      const int nn = t & 63, kk = t >> 6;
      #pragma unroll
      for (int i = 0; i < 4; ++i)
        Bs[kk + 4*i][nn] = Bm[(size_t)(k0 + kk + 4*i) * ldb + n0 + nn];
    }
    __syncthreads();
    #pragma unroll
    for (int kk = 0; kk < 16; ++kk) {
      float a[4], bb[4];
      #pragma unroll
      for (int i = 0; i < 4; ++i) a[i]  = As[kk][ty + 16*i];
      #pragma unroll
      for (int j = 0; j < 4; ++j) bb[j] = Bs[kk][tx + 16*j];
      #pragma unroll
      for (int i = 0; i < 4; ++i)
        #pragma unroll
        for (int j = 0; j < 4; ++j)
          acc[i][j] += a[i] * bb[j];
    }
    __syncthreads();
  }
  const long coff = (long)z * cBatch;
  #pragma unroll
  for (int i = 0; i < 4; ++i) {
    const int m = m0 + ty + 16*i;
    #pragma unroll
    for (int j = 0; j < 4; ++j) {
      const int n = n0 + tx + 16*j;
      float v = acc[i][j];
      if (bias) v += bias[n];
      if (pos)  v += pos[(size_t)(m & posmask) * N + n];
      if (ACT)  v = gelu_exact(v);
      if (OUTF32) ((float*)Cv)[coff + (size_t)m * N + n] = v;
      else        ((bf16*)Cv)[coff + (size_t)m * N + n] = f2bf(v);
    }
  }
}

// Fused attention: one wave per q row. scores(256) -> softmax -> PV(64).
// kp/vp layout: [b,h,d,p] f32. Output written in NATURAL [b,h,q,d] bf16 layout;
// the reference's transpose scramble is applied as a gather in norm1_kernel.
__global__ __launch_bounds__(256) void attn_kernel(
    const bf16* __restrict__ qb, const float* __restrict__ kp,
    const float* __restrict__ vp, const float* __restrict__ temp,
    bf16* __restrict__ xat)
{
  const int w = threadIdx.x >> 6, l = threadIdx.x & 63;
  const int b = blockIdx.z, h = blockIdx.y;
  const int qrow = blockIdx.x * 4 + w;
  __shared__ float shq[4][64];
  __shared__ float shp[4][256];
  shq[w][l] = bf2f(qb[((size_t)(b * N1_ + qrow)) * C_ + h * HD_ + l]);
  __syncthreads();
  const float* kpb = kp + ((size_t)(b * H_ + h)) * HD_ * P_;
  const float* vpb = vp + ((size_t)(b * H_ + h)) * HD_ * P_;
  const float tv = temp[h];
  float s0 = 0.f, s1 = 0.f, s2 = 0.f, s3 = 0.f;
  for (int d = 0; d < HD_; ++d) {
    const float qd = shq[w][d];         // broadcast, no conflict
    const float* kr = kpb + d * P_;
    s0 += qd * kr[l];
    s1 += qd * kr[l + 64];
    s2 += qd * kr[l + 128];
    s3 += qd * kr[l + 192];
  }
  s0 *= tv; s1 *= tv; s2 *= tv; s3 *= tv;
  float mx = fmaxf(fmaxf(s0, s1), fmaxf(s2, s3));
  #pragma unroll
  for (int off = 32; off > 0; off >>= 1) mx = fmaxf(mx, __shfl_xor(mx, off));
  const float e0 = expf(s0 - mx), e1 = expf(s1 - mx);
  const float e2 = expf(s2 - mx), e3 = expf(s3 - mx);
  float sm = e0 + e1 + e2 + e3;
  #pragma unroll
  for (int off = 32; off > 0; off >>= 1) sm += __shfl_xor(sm, off);
  const float inv = 1.0f / sm;
  shp[w][l]       = e0 * inv;
  shp[w][l + 64]  = e1 * inv;
  shp[w][l + 128] = e2 * inv;
  shp[w][l + 192] = e3 * inv;
  __syncthreads();
  const float4* vrow = (const float4*)(vpb + (size_t)l * P_);  // lane = d
  float acc = 0.f;
  for (int p4 = 0; p4 < P_ / 4; ++p4) {
    const float4 vv = vrow[p4];
    const float* pp = &shp[w][p4 * 4];  // broadcast
    acc += pp[0] * vv.x + pp[1] * vv.y + pp[2] * vv.z + pp[3] * vv.w;
  }
  xat[((size_t)((b * H_ + h) * N1_ + qrow)) * HD_ + l] = f2bf(acc);
}

// x = l2norm(scramble(attn_out) + q_skip). Row n of (b,4096): d=n>>6,
// h=(n>>3)&7, q=(n&7)*512+c. Gather from natural-layout xat.
__global__ __launch_bounds__(256) void norm1_kernel(
    const bf16* __restrict__ xat, const bf16* __restrict__ qb,
    bf16* __restrict__ xb)
{
  const int row = blockIdx.x;                  // b*4096 + n
  const int b = row >> 12, np = row & 4095;
  const int d = np >> 6, h = (np >> 3) & 7, qhi = np & 7;
  const int c0 = threadIdx.x, c1 = threadIdx.x + 256;
  const size_t sbase = (size_t)((b * H_ + h) * N1_ + qhi * 512);
  float v0 = bf2f(xat[(sbase + c0) * HD_ + d]) + bf2f(qb[(size_t)row * C_ + c0]);
  float v1 = bf2f(xat[(sbase + c1) * HD_ + d]) + bf2f(qb[(size_t)row * C_ + c1]);
  float ss = v0 * v0 + v1 * v1;
  #pragma unroll
  for (int off = 32; off > 0; off >>= 1) ss += __shfl_xor(ss, off);
  __shared__ float sw[4];
  if ((threadIdx.x & 63) == 0) sw[threadIdx.x >> 6] = ss;
  __syncthreads();
  const float tot = sw[0] + sw[1] + sw[2] + sw[3];
  const float scale = 1.0f / fmaxf(sqrtf(tot), 1e-12f);
  xb[(size_t)row * C_ + c0] = f2bf(v0 * scale);
  xb[(size_t)row * C_ + c1] = f2bf(v1 * scale);
}

// out = l2norm(y + x), y = h@W2 + b2 (f32). OUTPUT IS FLOAT32 (reference dtype).
__global__ __launch_bounds__(256) void norm2_kernel(
    const float* __restrict__ yb, const bf16* __restrict__ xb,
    float* __restrict__ outp)
{
  const int row = blockIdx.x;
  const int c0 = threadIdx.x, c1 = threadIdx.x + 256;
  float v0 = yb[(size_t)row * C_ + c0] + bf2f(xb[(size_t)row * C_ + c0]);
  float v1 = yb[(size_t)row * C_ + c1] + bf2f(xb[(size_t)row * C_ + c1]);
  float ss = v0 * v0 + v1 * v1;
  #pragma unroll
  for (int off = 32; off > 0; off >>= 1) ss += __shfl_xor(ss, off);
  __shared__ float sw[4];
  if ((threadIdx.x & 63) == 0) sw[threadIdx.x >> 6] = ss;
  __syncthreads();
  const float tot = sw[0] + sw[1] + sw[2] + sw[3];
  const float scale = 1.0f / fmaxf(sqrtf(tot), 1e-12f);
  outp[(size_t)row * C_ + c0] = v0 * scale;
  outp[(size_t)row * C_ + c1] = v1 * scale;
}

extern "C" void kernel_launch(void* const* d_in, const int* in_sizes, int n_in,
                              void* d_out, int out_size, void* d_ws, size_t ws_size,
                              hipStream_t stream)
{
  // Inputs are FLOAT32 (reference dtype); output is FLOAT32 (reference dtype).
  const float* x1   = (const float*)d_in[0];
  const float* x2   = (const float*)d_in[1];
  const float* Wq   = (const float*)d_in[2];
  const float* bq   = (const float*)d_in[3];
  const float* Wkv  = (const float*)d_in[4];
  const float* bkv  = (const float*)d_in[5];
  const float* Wp   = (const float*)d_in[6];
  const float* bp   = (const float*)d_in[7];
  const float* posq = (const float*)d_in[8];
  const float* posk = (const float*)d_in[9];
  const float* temp = (const float*)d_in[10];
  const float* W1   = (const float*)d_in[11];
  const float* b1   = (const float*)d_in[12];
  const float* W2   = (const float*)d_in[13];
  const float* b2   = (const float*)d_in[14];

  // Workspace layout — peak 120 MiB. Lifetimes: qb dead after norm1; kb dead
  // after kp-GEMM; vb dead after vp-GEMM; xat/kp/vp dead after norm1/attn.
  char* ws = (char*)d_ws;
  bf16*  qb  = (bf16*) (ws + 0);            // 32 MiB [0,32)
  bf16*  kb  = (bf16*) (ws + 33554432);     // 32 MiB [32,64)
  bf16*  vb  = (bf16*) (ws + 67108864);     // 32 MiB [64,96)
  float* kp  = (float*)(ws + 100663296);    // 4 MiB  [96,100)
  float* vp  = (float*)(ws + 104857600);    // 4 MiB  [100,104)
  bf16*  xat = (bf16*) (ws + 33554432);     // 32 MiB, aliases kb (dead)
  bf16*  xb  = (bf16*) (ws + 67108864);     // 32 MiB, aliases vb (dead)
  bf16*  hb  = (bf16*) (ws + 0);            // 32 MiB chunk, aliases qb (dead)
  float* yb  = (float*)(ws + 109051904);    // 16 MiB chunk [104,120)
  float* outp = (float*)d_out;

  const dim3 blk(256);
  const int Mrows = B_ * N1_;       // 32768
  const int CH = 8192;              // MLP row-chunk

  // q = x1@Wq + bq + pos_q   (f32 in, bf16 out)
  gemm_kernel<0,1,0,0><<<dim3(C_/64, Mrows/64, 1), blk, 0, stream>>>(
      x1, Wq, bq, posq, N1_-1, qb, Mrows, C_, C_, C_, C_, 0L, 1, 0, 0L);
  // k = x2@Wkv[:, :C] + bkv[:C] + pos_k
  gemm_kernel<0,1,0,0><<<dim3(C_/64, Mrows/64, 1), blk, 0, stream>>>(
      x2, Wkv, bkv, posk, N2_-1, kb, Mrows, C_, C_, C_, 2*C_, 0L, 1, 0, 0L);
  // v = x2@Wkv[:, C:] + bkv[C:]
  gemm_kernel<0,1,0,0><<<dim3(C_/64, Mrows/64, 1), blk, 0, stream>>>(
      x2, Wkv + C_, bkv + C_, nullptr, 0, vb, Mrows, C_, C_, C_, 2*C_, 0L, 1, 0, 0L);
  // kp[b,h,d,p] = sum_n k[b,n,h*64+d]*Wp[n,p] + bp   (f32 out, batch=64)
  gemm_kernel<1,0,1,0><<<dim3(P_/64, HD_/64, B_*H_), blk, 0, stream>>>(
      kb, Wp, bp, nullptr, 0, kp, HD_, P_, N2_, C_, P_,
      (long)N2_*C_, H_, HD_, (long)HD_*P_);
  // vp likewise from v
  gemm_kernel<1,0,1,0><<<dim3(P_/64, HD_/64, B_*H_), blk, 0, stream>>>(
      vb, Wp, bp, nullptr, 0, vp, HD_, P_, N2_, C_, P_,
      (long)N2_*C_, H_, HD_, (long)HD_*P_);
  // fused attention -> xat (natural layout, bf16). xat aliases kb (dead).
  attn_kernel<<<dim3(N1_/4, H_, B_), blk, 0, stream>>>(qb, kp, vp, temp, xat);
  // x = l2norm(scramble(attn) + q). xb aliases vb (dead).
  norm1_kernel<<<dim3(Mrows), blk, 0, stream>>>(xat, qb, xb);
  // MLP + final norm, chunked over rows to bound workspace. hb aliases qb.
  for (int c = 0; c < Mrows / CH; ++c) {
    const bf16* xc = xb + (size_t)c * CH * C_;
    gemm_kernel<0,0,0,1><<<dim3(MLP_/64, CH/64, 1), blk, 0, stream>>>(
        xc, W1, b1, nullptr, 0, hb, CH, MLP_, C_, C_, MLP_, 0L, 1, 0, 0L);
    gemm_kernel<0,0,1,0><<<dim3(C_/64, CH/64, 1), blk, 0, stream>>>(
        hb, W2, b2, nullptr, 0, yb, CH, C_, MLP_, MLP_, C_, 0L, 1, 0, 0L);
    norm2_kernel<<<dim3(CH), blk, 0, stream>>>(
        yb, xc, outp + (size_t)c * CH * C_);
  }
}

// Round 5
// 4970.591 us; speedup vs baseline: 1.5552x; 1.5552x over previous
//
#include <hip/hip_runtime.h>
#include <hip/hip_bf16.h>
#include <math.h>

// Problem constants
#define B_    8
#define N1_   4096
#define N2_   4096
#define C_    512
#define P_    256
#define H_    8
#define MLP_  2048
#define HD_   64

typedef __hip_bfloat16 bf16;

__device__ __forceinline__ float bf2f(bf16 v) { return __bfloat162float(v); }
__device__ __forceinline__ bf16  f2bf(float v) { return __float2bfloat16(v); }
__device__ __forceinline__ float ubf2f(unsigned short u) {
  union { float f; unsigned int i; } cv; cv.i = ((unsigned int)u) << 16; return cv.f;
}
__device__ __forceinline__ unsigned short f2bfu(float v) {
  union { bf16 b; unsigned short u; } cv; cv.b = __float2bfloat16(v); return cv.u;
}
__device__ __forceinline__ float gelu_exact(float x) {
  return 0.5f * x * (1.0f + erff(x * 0.70710678118654752f));
}

// Generic tiled GEMM: C = op(A) @ B (+bias +pos) with optional gelu.
// Inputs (x1/x2/weights/bias/pos) are FLOAT32; internal activations are bf16.
// AF32=1: A is f32. AF32=0: A is bf16 (internal buffers).
// TRANSA=0: A is (M,K) row-major. TRANSA=1: A is (K,M) row-major (kp/vp einsum,
//           bf16 only). B is always f32, (K,N) row-major.
// Batched over blockIdx.z: A offset = (z/aInnerCnt)*aOuter + (z%aInnerCnt)*aInner
// elements, C offset = z*cBatch. Tile 64x64, BK=16, 256 thr, 4x4/thr, tx+16j swizzle.
template<int TRANSA, int AF32, int OUTF32, int ACT>
__global__ __launch_bounds__(256) void gemm_kernel(
    const void* __restrict__ A, const float* __restrict__ Bm,
    const float* __restrict__ bias, const float* __restrict__ pos, int posmask,
    void* __restrict__ Cv, int M, int N, int K, int lda, int ldb,
    long aOuter, int aInnerCnt, int aInner, long cBatch)
{
  __shared__ float As[16][65];
  __shared__ float Bs[16][65];
  const int z = blockIdx.z;
  const long aoff = (long)(z / aInnerCnt) * aOuter + (long)(z % aInnerCnt) * aInner;
  const int n0 = blockIdx.x * 64;
  const int m0 = blockIdx.y * 64;
  const int t  = threadIdx.x;
  const int tx = t & 15, ty = t >> 4;
  float acc[4][4] = {};
  for (int k0 = 0; k0 < K; k0 += 16) {
    if (TRANSA) {   // bf16 A, (K,M) layout
      const bf16* Ab = (const bf16*)A + aoff;
      const int mm = t & 63, kk = t >> 6;
      #pragma unroll
      for (int i = 0; i < 4; ++i)
        As[kk + 4*i][mm] = bf2f(Ab[(size_t)(k0 + kk + 4*i) * lda + m0 + mm]);
    } else if (AF32) {   // f32 A, (M,K): 4 consecutive k per thread, 16B load
      const float* Ab = (const float*)A + aoff;
      const int mm = t >> 2, kk4 = (t & 3) * 4;
      const float4 av = *(const float4*)(Ab + (size_t)(m0 + mm) * lda + k0 + kk4);
      As[kk4+0][mm] = av.x;
      As[kk4+1][mm] = av.y;
      As[kk4+2][mm] = av.z;
      As[kk4+3][mm] = av.w;
    } else {             // bf16 A, (M,K): 8B vec load
      const bf16* Ab = (const bf16*)A + aoff;
      const int mm = t >> 2, kk4 = (t & 3) * 4;
      const ushort4 av = *(const ushort4*)(Ab + (size_t)(m0 + mm) * lda + k0 + kk4);
      As[kk4+0][mm] = ubf2f(av.x);
      As[kk4+1][mm] = ubf2f(av.y);
      As[kk4+2][mm] = ubf2f(av.z);
      As[kk4+3][mm] = ubf2f(av.w);
    }
    {
      const int nn = t & 63, kk = t >> 6;
      #pragma unroll
      for (int i = 0; i < 4; ++i)
        Bs[kk + 4*i][nn] = Bm[(size_t)(k0 + kk + 4*i) * ldb + n0 + nn];
    }
    __syncthreads();
    #pragma unroll
    for (int kk = 0; kk < 16; ++kk) {
      float a[4], bb[4];
      #pragma unroll
      for (int i = 0; i < 4; ++i) a[i]  = As[kk][ty + 16*i];
      #pragma unroll
      for (int j = 0; j < 4; ++j) bb[j] = Bs[kk][tx + 16*j];
      #pragma unroll
      for (int i = 0; i < 4; ++i)
        #pragma unroll
        for (int j = 0; j < 4; ++j)
          acc[i][j] += a[i] * bb[j];
    }
    __syncthreads();
  }
  const long coff = (long)z * cBatch;
  #pragma unroll
  for (int i = 0; i < 4; ++i) {
    const int m = m0 + ty + 16*i;
    #pragma unroll
    for (int j = 0; j < 4; ++j) {
      const int n = n0 + tx + 16*j;
      float v = acc[i][j];
      if (bias) v += bias[n];
      if (pos)  v += pos[(size_t)(m & posmask) * N + n];
      if (ACT)  v = gelu_exact(v);
      if (OUTF32) ((float*)Cv)[coff + (size_t)m * N + n] = v;
      else        ((bf16*)Cv)[coff + (size_t)m * N + n] = f2bf(v);
    }
  }
}

// Fused attention, LDS-tiled: one block = one (b,h) x 16 q-rows (4 waves x 4
// rows). Phase 1: kp[64][256] f32 staged in LDS; lane l owns p-cols 4l..4l+3;
// per d-step one ds_read_b128 (kp) + one float4 broadcast (qT) feeds 16 FMAs.
// Softmax in registers (shfl reduce over 64 lanes); P -> LDS as bf16.
// Phase 2: same LDS re-staged as vp transposed [p][d] (stride 65; staged with
// lane->p = l+64j so writes AND lane=d reads are bank-conflict-free).
// Output written in NATURAL [b,h,q,d] bf16 layout (norm1 does the scramble).
__global__ __launch_bounds__(256) void attn_kernel(
    const bf16* __restrict__ qb, const float* __restrict__ kp,
    const float* __restrict__ vp, const float* __restrict__ temp,
    bf16* __restrict__ xat)
{
  __shared__ float u[16640];                 // kpl[64][256] | vpl[256][65]
  __shared__ float shqT[64][20];             // q-tile transposed [d][row]
  __shared__ unsigned short shp[16][256];    // softmaxed P, bf16
  const int t = threadIdx.x;
  const int w = t >> 6, l = t & 63;
  const int b = blockIdx.z, h = blockIdx.y;
  const int q0 = blockIdx.x * 16;
  const float* kpb = kp + ((size_t)(b * H_ + h)) * HD_ * P_;
  const float* vpb = vp + ((size_t)(b * H_ + h)) * HD_ * P_;

  // stage q tile: shqT[d][r], r = 0..15 local row
  #pragma unroll
  for (int i = 0; i < 4; ++i) {
    const int lr = w + 4 * i;
    shqT[l][lr] = bf2f(qb[((size_t)(b * N1_ + q0 + lr)) * C_ + h * HD_ + l]);
  }
  // stage kpl[d][p] (contiguous f32, float4 both sides)
  {
    float4* dst = (float4*)u;
    const float4* src = (const float4*)kpb;
    #pragma unroll
    for (int i = 0; i < 16; ++i) dst[i * 256 + t] = src[i * 256 + t];
  }
  __syncthreads();

  // phase 1: scores s[ri][j], row = q0+4w+ri, p = 4l+j
  float s[4][4] = {};
  #pragma unroll 4
  for (int d = 0; d < 64; ++d) {
    const float4 kv = *(const float4*)&u[d * 256 + 4 * l];
    const float4 qv = *(const float4*)&shqT[d][4 * w];
    s[0][0] += qv.x * kv.x; s[0][1] += qv.x * kv.y; s[0][2] += qv.x * kv.z; s[0][3] += qv.x * kv.w;
    s[1][0] += qv.y * kv.x; s[1][1] += qv.y * kv.y; s[1][2] += qv.y * kv.z; s[1][3] += qv.y * kv.w;
    s[2][0] += qv.z * kv.x; s[2][1] += qv.z * kv.y; s[2][2] += qv.z * kv.z; s[2][3] += qv.z * kv.w;
    s[3][0] += qv.w * kv.x; s[3][1] += qv.w * kv.y; s[3][2] += qv.w * kv.z; s[3][3] += qv.w * kv.w;
  }
  const float tv = temp[h];
  #pragma unroll
  for (int ri = 0; ri < 4; ++ri) {
    float a0 = s[ri][0] * tv, a1 = s[ri][1] * tv;
    float a2 = s[ri][2] * tv, a3 = s[ri][3] * tv;
    float m = fmaxf(fmaxf(a0, a1), fmaxf(a2, a3));
    #pragma unroll
    for (int off = 32; off > 0; off >>= 1) m = fmaxf(m, __shfl_xor(m, off));
    const float e0 = __expf(a0 - m), e1 = __expf(a1 - m);
    const float e2 = __expf(a2 - m), e3 = __expf(a3 - m);
    float sm = e0 + e1 + e2 + e3;
    #pragma unroll
    for (int off = 32; off > 0; off >>= 1) sm += __shfl_xor(sm, off);
    const float inv = 1.0f / sm;
    ushort4 pk;
    pk.x = f2bfu(e0 * inv); pk.y = f2bfu(e1 * inv);
    pk.z = f2bfu(e2 * inv); pk.w = f2bfu(e3 * inv);
    *(ushort4*)&shp[4 * w + ri][4 * l] = pk;   // 8B/lane, conflict-free
  }
  __syncthreads();   // all waves done reading kpl

  // stage vpl[p][d] transposed, stride 65. lane p = l+64j, wave-quarter owns d.
  #pragma unroll
  for (int i = 0; i < 16; ++i) {
    const int d = i * 4 + w;
    const float* vr = vpb + d * P_;
    u[(l      ) * 65 + d] = vr[l      ];
    u[(l +  64) * 65 + d] = vr[l +  64];
    u[(l + 128) * 65 + d] = vr[l + 128];
    u[(l + 192) * 65 + d] = vr[l + 192];
  }
  __syncthreads();

  // phase 2: out[ri][d], lane = d. P broadcast (ushort4) x vpl column reads.
  float o[4] = {0.f, 0.f, 0.f, 0.f};
  #pragma unroll 4
  for (int g = 0; g < 64; ++g) {
    const float v0 = u[(4 * g + 0) * 65 + l];
    const float v1 = u[(4 * g + 1) * 65 + l];
    const float v2 = u[(4 * g + 2) * 65 + l];
    const float v3 = u[(4 * g + 3) * 65 + l];
    #pragma unroll
    for (int ri = 0; ri < 4; ++ri) {
      const ushort4 pw = *(const ushort4*)&shp[4 * w + ri][4 * g];
      o[ri] += ubf2f(pw.x) * v0 + ubf2f(pw.y) * v1
             + ubf2f(pw.z) * v2 + ubf2f(pw.w) * v3;
    }
  }
  const size_t rbase = (size_t)(b * H_ + h) * N1_ + q0 + 4 * w;
  #pragma unroll
  for (int ri = 0; ri < 4; ++ri)
    xat[(rbase + ri) * HD_ + l] = f2bf(o[ri]);
}

// x = l2norm(scramble(attn_out) + q_skip). Row n of (b,4096): d=n>>6,
// h=(n>>3)&7, q=(n&7)*512+c. Gather from natural-layout xat.
__global__ __launch_bounds__(256) void norm1_kernel(
    const bf16* __restrict__ xat, const bf16* __restrict__ qb,
    bf16* __restrict__ xb)
{
  const int row = blockIdx.x;                  // b*4096 + n
  const int b = row >> 12, np = row & 4095;
  const int d = np >> 6, h = (np >> 3) & 7, qhi = np & 7;
  const int c0 = threadIdx.x, c1 = threadIdx.x + 256;
  const size_t sbase = (size_t)((b * H_ + h) * N1_ + qhi * 512);
  float v0 = bf2f(xat[(sbase + c0) * HD_ + d]) + bf2f(qb[(size_t)row * C_ + c0]);
  float v1 = bf2f(xat[(sbase + c1) * HD_ + d]) + bf2f(qb[(size_t)row * C_ + c1]);
  float ss = v0 * v0 + v1 * v1;
  #pragma unroll
  for (int off = 32; off > 0; off >>= 1) ss += __shfl_xor(ss, off);
  __shared__ float sw[4];
  if ((threadIdx.x & 63) == 0) sw[threadIdx.x >> 6] = ss;
  __syncthreads();
  const float tot = sw[0] + sw[1] + sw[2] + sw[3];
  const float scale = 1.0f / fmaxf(sqrtf(tot), 1e-12f);
  xb[(size_t)row * C_ + c0] = f2bf(v0 * scale);
  xb[(size_t)row * C_ + c1] = f2bf(v1 * scale);
}

// out = l2norm(y + x), y = h@W2 + b2 (f32). OUTPUT IS FLOAT32 (reference dtype).
__global__ __launch_bounds__(256) void norm2_kernel(
    const float* __restrict__ yb, const bf16* __restrict__ xb,
    float* __restrict__ outp)
{
  const int row = blockIdx.x;
  const int c0 = threadIdx.x, c1 = threadIdx.x + 256;
  float v0 = yb[(size_t)row * C_ + c0] + bf2f(xb[(size_t)row * C_ + c0]);
  float v1 = yb[(size_t)row * C_ + c1] + bf2f(xb[(size_t)row * C_ + c1]);
  float ss = v0 * v0 + v1 * v1;
  #pragma unroll
  for (int off = 32; off > 0; off >>= 1) ss += __shfl_xor(ss, off);
  __shared__ float sw[4];
  if ((threadIdx.x & 63) == 0) sw[threadIdx.x >> 6] = ss;
  __syncthreads();
  const float tot = sw[0] + sw[1] + sw[2] + sw[3];
  const float scale = 1.0f / fmaxf(sqrtf(tot), 1e-12f);
  outp[(size_t)row * C_ + c0] = v0 * scale;
  outp[(size_t)row * C_ + c1] = v1 * scale;
}

extern "C" void kernel_launch(void* const* d_in, const int* in_sizes, int n_in,
                              void* d_out, int out_size, void* d_ws, size_t ws_size,
                              hipStream_t stream)
{
  // Inputs are FLOAT32 (reference dtype); output is FLOAT32 (reference dtype).
  const float* x1   = (const float*)d_in[0];
  const float* x2   = (const float*)d_in[1];
  const float* Wq   = (const float*)d_in[2];
  const float* bq   = (const float*)d_in[3];
  const float* Wkv  = (const float*)d_in[4];
  const float* bkv  = (const float*)d_in[5];
  const float* Wp   = (const float*)d_in[6];
  const float* bp   = (const float*)d_in[7];
  const float* posq = (const float*)d_in[8];
  const float* posk = (const float*)d_in[9];
  const float* temp = (const float*)d_in[10];
  const float* W1   = (const float*)d_in[11];
  const float* b1   = (const float*)d_in[12];
  const float* W2   = (const float*)d_in[13];
  const float* b2   = (const float*)d_in[14];

  // Workspace layout — peak 120 MiB. Lifetimes: qb dead after norm1; kb dead
  // after kp-GEMM; vb dead after vp-GEMM; xat/kp/vp dead after norm1/attn.
  char* ws = (char*)d_ws;
  bf16*  qb  = (bf16*) (ws + 0);            // 32 MiB [0,32)
  bf16*  kb  = (bf16*) (ws + 33554432);     // 32 MiB [32,64)
  bf16*  vb  = (bf16*) (ws + 67108864);     // 32 MiB [64,96)
  float* kp  = (float*)(ws + 100663296);    // 4 MiB  [96,100)
  float* vp  = (float*)(ws + 104857600);    // 4 MiB  [100,104)
  bf16*  xat = (bf16*) (ws + 33554432);     // 32 MiB, aliases kb (dead)
  bf16*  xb  = (bf16*) (ws + 67108864);     // 32 MiB, aliases vb (dead)
  bf16*  hb  = (bf16*) (ws + 0);            // 32 MiB chunk, aliases qb (dead)
  float* yb  = (float*)(ws + 109051904);    // 16 MiB chunk [104,120)
  float* outp = (float*)d_out;

  const dim3 blk(256);
  const int Mrows = B_ * N1_;       // 32768
  const int CH = 8192;              // MLP row-chunk

  // q = x1@Wq + bq + pos_q   (f32 in, bf16 out)
  gemm_kernel<0,1,0,0><<<dim3(C_/64, Mrows/64, 1), blk, 0, stream>>>(
      x1, Wq, bq, posq, N1_-1, qb, Mrows, C_, C_, C_, C_, 0L, 1, 0, 0L);
  // k = x2@Wkv[:, :C] + bkv[:C] + pos_k
  gemm_kernel<0,1,0,0><<<dim3(C_/64, Mrows/64, 1), blk, 0, stream>>>(
      x2, Wkv, bkv, posk, N2_-1, kb, Mrows, C_, C_, C_, 2*C_, 0L, 1, 0, 0L);
  // v = x2@Wkv[:, C:] + bkv[C:]
  gemm_kernel<0,1,0,0><<<dim3(C_/64, Mrows/64, 1), blk, 0, stream>>>(
      x2, Wkv + C_, bkv + C_, nullptr, 0, vb, Mrows, C_, C_, C_, 2*C_, 0L, 1, 0, 0L);
  // kp[b,h,d,p] = sum_n k[b,n,h*64+d]*Wp[n,p] + bp   (f32 out, batch=64)
  gemm_kernel<1,0,1,0><<<dim3(P_/64, HD_/64, B_*H_), blk, 0, stream>>>(
      kb, Wp, bp, nullptr, 0, kp, HD_, P_, N2_, C_, P_,
      (long)N2_*C_, H_, HD_, (long)HD_*P_);
  // vp likewise from v
  gemm_kernel<1,0,1,0><<<dim3(P_/64, HD_/64, B_*H_), blk, 0, stream>>>(
      vb, Wp, bp, nullptr, 0, vp, HD_, P_, N2_, C_, P_,
      (long)N2_*C_, H_, HD_, (long)HD_*P_);
  // fused attention -> xat (natural layout, bf16). xat aliases kb (dead).
  attn_kernel<<<dim3(N1_/16, H_, B_), blk, 0, stream>>>(qb, kp, vp, temp, xat);
  // x = l2norm(scramble(attn) + q). xb aliases vb (dead).
  norm1_kernel<<<dim3(Mrows), blk, 0, stream>>>(xat, qb, xb);
  // MLP + final norm, chunked over rows to bound workspace. hb aliases qb.
  for (int c = 0; c < Mrows / CH; ++c) {
    const bf16* xc = xb + (size_t)c * CH * C_;
    gemm_kernel<0,0,0,1><<<dim3(MLP_/64, CH/64, 1), blk, 0, stream>>>(
        xc, W1, b1, nullptr, 0, hb, CH, MLP_, C_, C_, MLP_, 0L, 1, 0, 0L);
    gemm_kernel<0,0,1,0><<<dim3(C_/64, CH/64, 1), blk, 0, stream>>>(
        hb, W2, b2, nullptr, 0, yb, CH, C_, MLP_, MLP_, C_, 0L, 1, 0, 0L);
    norm2_kernel<<<dim3(CH), blk, 0, stream>>>(
        yb, xc, outp + (size_t)c * CH * C_);
  }
}